// Round 11
// baseline (724.367 us; speedup 1.0000x reference)
//
#include <hip/hip_runtime.h>
#include <hip/hip_bf16.h>
#include <cstdint>

// Problem constants (static per reference: counts are all T/E = 2048)
#define E_   8
#define D_   768
#define H_   3072
#define T_   16384
#define SEG  2048
#define PSEG (SEG + 2)   // +1 zero guard row above and below each segment

typedef __attribute__((ext_vector_type(8))) __bf16 bf16x8;
typedef __attribute__((ext_vector_type(4))) float f32x4;
typedef __attribute__((ext_vector_type(4))) unsigned int u32x4;

__device__ inline unsigned short f2bf(float f) {
  union { float f; unsigned int u; } v; v.f = f;
  unsigned int u = v.u;
  u += 0x7fffu + ((u >> 16) & 1u);   // round-to-nearest-even
  return (unsigned short)(u >> 16);
}

// branch-free tanh-form GELU: x * sigmoid(1.5957691*x*(1+0.044715*x^2))
__device__ inline float gelu_fast(float x) {
  const float a = -2.302118131f;           // -2*0.7978845608*log2(e)
  const float b = -0.102944213f;           // a*0.044715
  float z = x * __builtin_fmaf(b, x * x, a);
  float e = __builtin_amdgcn_exp2f(z);
  return x * __builtin_amdgcn_rcpf(1.0f + e);
}

// packed f32x2 -> bf16x2 (RNE, same as f2bf); low 16 = s0, high 16 = s1
__device__ inline unsigned cvt_pk_bf16(float lo, float hi) {
  unsigned r;
  asm("v_cvt_pk_bf16_f32 %0, %1, %2" : "=v"(r) : "v"(lo), "v"(hi));
  return r;
}

// async global->LDS, 16B per lane; LDS dest is wave-uniform base + lane*16
__device__ inline void gload16(const unsigned short* g, unsigned short* l) {
  __builtin_amdgcn_global_load_lds(
      (const __attribute__((address_space(1))) unsigned int*)g,
      (__attribute__((address_space(3))) unsigned int*)l, 16, 0, 0);
}

// ---- fp32 -> bf16, into padded [E][PSEG][D] layout ----
__global__ __launch_bounds__(256) void cvt_x_pad_kernel(const float* __restrict__ in,
                                                        unsigned short* __restrict__ out) {
  const int i = blockIdx.x * 256 + threadIdx.x;       // 8-element vector index
  const int elem = i * 8;
  const int row = elem / D_;
  const int col = elem - row * D_;
  const int prow = (row >> 11) * PSEG + 1 + (row & (SEG - 1));
  const float* p = in + (size_t)row * D_ + col;
  u32x4 v;
#pragma unroll
  for (int j = 0; j < 4; ++j)
    v[j] = (unsigned)f2bf(p[2 * j]) | ((unsigned)f2bf(p[2 * j + 1]) << 16);
  *(u32x4*)(out + (size_t)prow * D_ + col) = v;
}

// ---- zero the guard rows of BOTH padded buffers in one launch ----
__global__ __launch_bounds__(256) void zero_guards2_kernel(unsigned short* __restrict__ Xp,
                                                           unsigned short* __restrict__ Hp) {
  const int b = blockIdx.x;           // 0..15: Xp, 16..31: Hp
  unsigned short* buf = (b < 16) ? Xp : Hp;
  const int C = (b < 16) ? D_ : H_;
  const int bb = b & 15;
  const int e = bb >> 1;
  const size_t row = (size_t)e * PSEG + (bb & 1) * (PSEG - 1);
  for (int c = threadIdx.x; c < C; c += 256) buf[row * C + c] = 0;
}

// ---- weight transpose: [R][C][3] f32 -> [R][3][C] bf16, 8-wide vectorized ----
template <int C>
__global__ __launch_bounds__(256) void cvt_w_kernel(const float* __restrict__ in,
                                                    unsigned short* __restrict__ out) {
  constexpr int C8 = C / 8;
  const int i = blockIdx.x * 256 + threadIdx.x;
  const int row = i / C8;
  const int cq = i - row * C8;
  const float* src = in + ((size_t)row * C + cq * 8) * 3;
  unsigned short* dst = out + (size_t)row * 3 * C + cq * 8;
  f32x4 v[6];
#pragma unroll
  for (int j = 0; j < 6; ++j) v[j] = *(const f32x4*)(src + j * 4);
  const float* f = (const float*)v;
#pragma unroll
  for (int k = 0; k < 3; ++k) {
    u32x4 w;
#pragma unroll
    for (int j = 0; j < 4; ++j)
      w[j] = (unsigned)f2bf(f[(2 * j) * 3 + k]) |
             ((unsigned)f2bf(f[(2 * j + 1) * 3 + k]) << 16);
    *(u32x4*)(dst + k * C) = w;
  }
}

// ============================================================================
// GEMM1: 256x256 8-phase conv-GEMM, FOUR waves (2Mx2N), wave-tile 128x128.
//   256 thr; acc[8][8] f32x4 (256 f32/lane, unified file, 1 wave/SIMD).
//   LDS reads/K-tile: 4x(128+128)x64x2 = 128 KB (-33% vs 8-wave) -> MFMA floor.
// Schedule/slots/regions/vmcnt = round-9/10 audited structure; per-stage-call
// gloads double (2->4, 256 thr), so all vmcnt counts double (6->12, 4->8).
// ============================================================================
template <int CIN, int COUT, bool DO_GELU>
__global__ __launch_bounds__(256, 1) void conv_gemm4_kernel(
    const unsigned short* __restrict__ A,
    const unsigned short* __restrict__ Bt,
    const float* __restrict__ bias,
    void* __restrict__ Out) {
  __shared__ __align__(16) unsigned short lds[65536];  // 128 KiB

  constexpr int CSTEPS = CIN / 64;
  constexpr int NT = 3 * CSTEPS;        // K-tiles
  constexpr int NTN = COUT / 256;       // n-tiles per expert

  const int tid  = threadIdx.x;
  const int wid  = tid >> 6, lane = tid & 63;
  const int wm   = wid >> 1, wn = wid & 1;

  const int bid = blockIdx.x;
  const int e   = bid & 7;              // expert == XCD
  const int rem = bid >> 3;             // 4-m-chunked
  const int mc  = rem / (4 * NTN);
  const int r2  = rem - mc * 4 * NTN;
  const int m0  = (mc * 4 + (r2 & 3)) * 256;
  const int n0  = (r2 >> 2) * 256;

  const int rowoff = tid >> 3;                         // 0..31: staging row-in-32
  const int psrc   = ((lane & 7) ^ (lane >> 3)) * 8;   // source-permuted piece (elems)
  const int ko     = (lane >> 4) * 16;                 // frag k-col byte offset
  const int ax     = (lane & 7) << 4;                  // read-side XOR
  const int l15    = lane & 15;

  // precomputed per-lane LDS read pointers; s-variant via disjoint-bit identity
  const int koax0 = ko ^ ax;
  const int koax1 = (64 | ko) ^ ax;
  const char* pA0 = (const char*)lds + wm * 16384 + l15 * 128 + koax0;
  const char* pA1 = (const char*)lds + wm * 16384 + l15 * 128 + koax1;
  const char* pB0 = (const char*)lds + 65536 + wn * 16384 + l15 * 128 + koax0;
  const char* pB1 = (const char*)lds + 65536 + wn * 16384 + l15 * 128 + koax1;

  // staging: uniform base + per-lane 32-bit voffset
  const unsigned short* aU = A + ((size_t)e * PSEG + m0) * CIN;
  const unsigned short* bU = Bt + (size_t)(e * COUT + n0) * 3 * CIN;
  const int avo = rowoff * CIN + psrc;
  const int bvo = rowoff * 3 * CIN + psrc;
  size_t aOff = 0, bOff = 0;

  f32x4 acc[8][8];
#pragma unroll
  for (int n = 0; n < 8; ++n) {
    const float bv = bias[e * COUT + n0 + wn * 128 + n * 16 + l15];
#pragma unroll
    for (int m = 0; m < 8; ++m) acc[m][n] = (f32x4){bv, bv, bv, bv};
  }

#define STAGE_A(BUF_, part_) do {                                                    \
    _Pragma("unroll")                                                                \
    for (int ii_ = 0; ii_ < 2; ++ii_)                                                \
      _Pragma("unroll")                                                              \
      for (int j_ = 0; j_ < 2; ++j_)                                                 \
        gload16(aU + aOff + avo + (ii_ * 128 + (part_) * 64 + j_ * 32) * CIN,        \
                (unsigned short*)((char*)lds + (BUF_) * 32768 + ii_ * 16384 +        \
                                  (part_) * 8192 + j_ * 4096 + wid * 1024 +          \
                                  lane * 16));                                       \
  } while (0)

#define STAGE_B(BUF_, h_) do {                                                       \
    _Pragma("unroll")                                                                \
    for (int ii_ = 0; ii_ < 2; ++ii_)                                                \
      _Pragma("unroll")                                                              \
      for (int j_ = 0; j_ < 2; ++j_)                                                 \
        gload16(bU + bOff + bvo + ((h_) * 128 + ii_ * 64 + j_ * 32) * 3 * CIN,       \
                (unsigned short*)((char*)lds + 65536 + (BUF_) * 32768 +              \
                                  (h_) * 16384 + ii_ * 8192 + j_ * 4096 +            \
                                  wid * 1024 + lane * 16));                          \
  } while (0)

#define ADVA(nx_) do { if ((nx_) < NT) aOff += 64; } while (0)
#define ADVB(nx_) do { if ((nx_) < NT) bOff += 64; } while (0)

#define FULLBAR() do { asm volatile("" ::: "memory");                                \
                       __builtin_amdgcn_s_barrier();                                 \
                       asm volatile("" ::: "memory"); } while (0)
#define VMA() asm volatile("s_waitcnt vmcnt(12)" ::: "memory")
#define VMB() asm volatile("s_waitcnt vmcnt(8)" ::: "memory")
#define VM_NONE()

#define RA(buf_, mh_, s_, raA_, raB_, RB_) do {                                      \
    const char* pAx_ = (s_) ? pA1 : pA0;                                             \
    if (RB_) {                                                                       \
      const char* pBx_ = (s_) ? pB1 : pB0;                                           \
      _Pragma("unroll")                                                              \
      for (int n_ = 0; n_ < 8; ++n_)                                                 \
        raB_[n_] = *(const bf16x8*)(pBx_ + (buf_) * 32768 + n_ * 2048);              \
    }                                                                                \
    _Pragma("unroll")                                                                \
    for (int mi_ = 0; mi_ < 4; ++mi_)                                                \
      raA_[mi_] = *(const bf16x8*)(pAx_ + (buf_) * 32768 + (mh_) * 8192 +            \
                                   mi_ * 2048);                                      \
  } while (0)

#define PHASE(raBuf_, raMh_, raS_, raA_, raB_, RB_, useA_, useB_, mh_, STAGE_STMT, VMW_) \
  do {                                                                               \
    FULLBAR();                                                                       \
    RA(raBuf_, raMh_, raS_, raA_, raB_, RB_);                                        \
    STAGE_STMT;                                                                      \
    __builtin_amdgcn_s_setprio(1);                                                   \
    _Pragma("unroll")                                                                \
    for (int mi_ = 0; mi_ < 4; ++mi_)                                                \
      _Pragma("unroll")                                                              \
      for (int n_ = 0; n_ < 8; ++n_)                                                 \
        acc[(mh_) * 4 + mi_][n_] = __builtin_amdgcn_mfma_f32_16x16x32_bf16(          \
            useA_[mi_], useB_[n_], acc[(mh_) * 4 + mi_][n_], 0, 0, 0);               \
    __builtin_amdgcn_s_setprio(0);                                                   \
    VMW_();                                                                          \
  } while (0)

  // ---- prologue (same slot order as round 9/10; counts doubled) ----
  STAGE_B(0, 0); STAGE_B(0, 1); ADVB(1);
  STAGE_A(0, 0); STAGE_A(0, 1); ADVA(1);
  STAGE_B(1, 0); STAGE_B(1, 1); ADVB(2);
  VMA();   // 24 outstanding, keep 12 -> drains B(0)+A(0,P0)
  FULLBAR();

  bf16x8 aX[4], aY[4], bF0[8], bF1[8];
  RA(0, 0, 0, aX, bF0, 1);

  int kt0 = 0;
#pragma unroll 1
  for (int it = 0; it < NT / 2; ++it, kt0 += 2) {
    PHASE(0, 0, 1, aY, bF1, 1, aX, bF0, 0, STAGE_A(1, 0), VMA);
    PHASE(0, 1, 0, aX, bF0, 0, aY, bF1, 0, { STAGE_A(1, 1); ADVA(kt0 + 2); }, VM_NONE);
    PHASE(0, 1, 1, aY, bF1, 0, aX, bF0, 1, STAGE_B(0, 0), VMB);
    PHASE(1, 0, 0, aX, bF0, 1, aY, bF1, 1, { STAGE_B(0, 1); ADVB(kt0 + 3); }, VM_NONE);
    PHASE(1, 0, 1, aY, bF1, 1, aX, bF0, 0, STAGE_A(0, 0), VMA);
    PHASE(1, 1, 0, aX, bF0, 0, aY, bF1, 0, { STAGE_A(0, 1); ADVA(kt0 + 3); }, VM_NONE);
    PHASE(1, 1, 1, aY, bF1, 0, aX, bF0, 1, STAGE_B(1, 0), VMB);
    PHASE(0, 0, 0, aX, bF0, 1, aY, bF1, 1, { STAGE_B(1, 1); ADVB(kt0 + 4); }, VM_NONE);
  }

  asm volatile("s_waitcnt vmcnt(0)" ::: "memory");

#undef PHASE
#undef RA
#undef STAGE_A
#undef STAGE_B
#undef ADVA
#undef ADVB

  // ---- epilogue: C/D layout col=lane&15, row=(lane>>4)*4+i; cvt_pk pairs ----
#pragma unroll
  for (int m = 0; m < 8; ++m) {
    const int rowb = m0 + wm * 128 + m * 16 + ((lane >> 4) << 2);
#pragma unroll
    for (int n = 0; n < 8; ++n) {
      const int col = n0 + wn * 128 + n * 16 + l15;
      if (DO_GELU) {
        unsigned short* ob = (unsigned short*)Out +
                             ((size_t)e * PSEG + 1 + rowb) * COUT + col;
#pragma unroll
        for (int i = 0; i < 4; i += 2) {
          const unsigned pk = cvt_pk_bf16(gelu_fast(acc[m][n][i]),
                                          gelu_fast(acc[m][n][i + 1]));
          ob[(size_t)i * COUT] = (unsigned short)pk;
          ob[(size_t)(i + 1) * COUT] = (unsigned short)(pk >> 16);
        }
      } else {
        float* ob = (float*)Out + ((size_t)e * SEG + rowb) * COUT + col;
#pragma unroll
        for (int i = 0; i < 4; ++i) ob[(size_t)i * COUT] = acc[m][n][i];
      }
    }
  }
#undef FULLBAR
#undef VMA
#undef VMB
#undef VM_NONE
}

// ============================================================================
// GEMM2: 256x192-tile, FOUR waves (2Mx2N), wave-tile 128x96 -> 256 blocks.
//   acc[8][6] (192 f32/lane). Round-8/9/10 audited schedule; per-stage-call
//   gloads double (1->2) so vmcnt counts double (2->4, 3->6).
// ============================================================================
template <int CIN, int COUT>
__global__ __launch_bounds__(256, 1) void conv_gemm4_n192_kernel(
    const unsigned short* __restrict__ A,
    const unsigned short* __restrict__ Bt,
    const float* __restrict__ bias,
    float* __restrict__ Out) {
  __shared__ __align__(16) unsigned short lds[57344];  // 112 KiB

  constexpr int CSTEPS = CIN / 64;      // 48
  constexpr int NT = 3 * CSTEPS;        // 144

  const int tid  = threadIdx.x;
  const int wid  = tid >> 6, lane = tid & 63;
  const int wm   = wid >> 1, wn = wid & 1;

  const int bid = blockIdx.x;
  const int e   = bid & 7;              // expert == XCD (32 blocks/XCD)
  const int rem = bid >> 3;             // 0..31: m-inner (8) x n (4)
  const int m0  = (rem & 7) * 256;
  const int n0  = (rem >> 3) * 192;

  const int rowoff = tid >> 3;          // 0..31
  const int psrc   = ((lane & 7) ^ (lane >> 3)) * 8;
  const int ko     = (lane >> 4) * 16;
  const int ax     = (lane & 7) << 4;
  const int l15    = lane & 15;

  const int koax0 = ko ^ ax;
  const int koax1 = (64 | ko) ^ ax;
  const char* pA0 = (const char*)lds + wm * 16384 + l15 * 128 + koax0;
  const char* pA1 = (const char*)lds + wm * 16384 + l15 * 128 + koax1;
  const char* pB0 = (const char*)lds + 65536 + wn * 12288 + l15 * 128 + koax0;
  const char* pB1 = (const char*)lds + 65536 + wn * 12288 + l15 * 128 + koax1;

  const unsigned short* aU = A + ((size_t)e * PSEG + m0) * CIN;
  const unsigned short* bU = Bt + (size_t)(e * COUT + n0) * 3 * CIN;
  const int avo = rowoff * CIN + psrc;
  const int bvo = rowoff * 3 * CIN + psrc;
  size_t aOff = 0, bOff = 0;

  f32x4 acc[8][6];
#pragma unroll
  for (int n = 0; n < 6; ++n) {
    const float bv = bias[e * COUT + n0 + wn * 96 + n * 16 + l15];
#pragma unroll
    for (int m = 0; m < 8; ++m) acc[m][n] = (f32x4){bv, bv, bv, bv};
  }

#define ADVA(nx_) do { if ((nx_) < NT) aOff += 64; } while (0)
#define ADVB(nx_) do { if ((nx_) < NT) bOff += 64; } while (0)

  // A: 4 slots of 64 rows; linear [256][64] per buf (32 KiB)
#define STAGE_A2(BUF_, slot_) do {                                                   \
    _Pragma("unroll")                                                                \
    for (int j_ = 0; j_ < 2; ++j_)                                                   \
      gload16(aU + aOff + avo + ((slot_) * 64 + j_ * 32) * CIN,                      \
              (unsigned short*)((char*)lds + (BUF_) * 32768 + (slot_) * 8192 +       \
                                j_ * 4096 + wid * 1024 + lane * 16));                \
  } while (0)
  // B: 3 slots of 64 rows; linear [192][64] per buf (24 KiB) at byte 65536
#define STAGE_B2(BUF_, slot_) do {                                                   \
    _Pragma("unroll")                                                                \
    for (int j_ = 0; j_ < 2; ++j_)                                                   \
      gload16(bU + bOff + bvo + ((slot_) * 64 + j_ * 32) * 3 * CIN,                  \
              (unsigned short*)((char*)lds + 65536 + (BUF_) * 24576 +                \
                                (slot_) * 8192 + j_ * 4096 + wid * 1024 +            \
                                lane * 16));                                         \
  } while (0)

#define FULLBAR() do { asm volatile("" ::: "memory");                                \
                       __builtin_amdgcn_s_barrier();                                 \
                       asm volatile("" ::: "memory"); } while (0)
#define VM6() asm volatile("s_waitcnt vmcnt(6)" ::: "memory")
#define VM4() asm volatile("s_waitcnt vmcnt(4)" ::: "memory")

#define RA_A2(buf_, mh_, s_, dst_) do {                                              \
    const char* pAx_ = (s_) ? pA1 : pA0;                                             \
    _Pragma("unroll")                                                                \
    for (int mi_ = 0; mi_ < 4; ++mi_)                                                \
      dst_[mi_] = *(const bf16x8*)(pAx_ + (buf_) * 32768 + (mh_) * 8192 +            \
                                   mi_ * 2048);                                      \
  } while (0)

#define RA_B2(buf_, s_, dst_) do {                                                   \
    const char* pBx_ = (s_) ? pB1 : pB0;                                             \
    _Pragma("unroll")                                                                \
    for (int n_ = 0; n_ < 6; ++n_)                                                   \
      dst_[n_] = *(const bf16x8*)(pBx_ + (buf_) * 24576 + n_ * 2048);                \
  } while (0)

#define MFMA24(mh_, aU_, bU_) do {                                                   \
    __builtin_amdgcn_s_setprio(1);                                                   \
    _Pragma("unroll")                                                                \
    for (int mi_ = 0; mi_ < 4; ++mi_)                                                \
      _Pragma("unroll")                                                              \
      for (int n_ = 0; n_ < 6; ++n_)                                                 \
        acc[(mh_) * 4 + mi_][n_] = __builtin_amdgcn_mfma_f32_16x16x32_bf16(          \
            aU_[mi_], bU_[n_], acc[(mh_) * 4 + mi_][n_], 0, 0, 0);                   \
    __builtin_amdgcn_s_setprio(0);                                                   \
  } while (0)

  // ---- prologue: A(0)x4, B(0)x3, B(1)x3; vmcnt(6) keeps B(1); barrier; prime ----
  STAGE_A2(0, 0); STAGE_A2(0, 1); STAGE_A2(0, 2); STAGE_A2(0, 3); ADVA(1);
  STAGE_B2(0, 0); STAGE_B2(0, 1); STAGE_B2(0, 2); ADVB(1);
  STAGE_B2(1, 0); STAGE_B2(1, 1); STAGE_B2(1, 2); ADVB(2);
  VM6();
  FULLBAR();

  bf16x8 aX[4], aY[4], bF0[6], bF1[6];
  RA_A2(0, 0, 0, aX);
  RA_B2(0, 0, bF0);

  int kt0 = 0;
#pragma unroll 1
  for (int it = 0; it < NT / 2; ++it, kt0 += 2) {
    // tile t (buf0)
    FULLBAR(); RA_A2(0, 0, 1, aY); RA_B2(0, 1, bF1);
               STAGE_A2(1, 0); STAGE_A2(1, 1); STAGE_A2(1, 2); STAGE_A2(1, 3);
               ADVA(kt0 + 2); MFMA24(0, aX, bF0);
    FULLBAR(); RA_A2(0, 1, 0, aX); MFMA24(0, aY, bF1);
    FULLBAR(); RA_A2(0, 1, 1, aY); STAGE_B2(0, 0); STAGE_B2(0, 1);
               MFMA24(1, aX, bF0); VM4();
    FULLBAR(); RA_A2(1, 0, 0, aX); RA_B2(1, 0, bF0); STAGE_B2(0, 2);
               ADVB(kt0 + 3); MFMA24(1, aY, bF1);
    // tile t+1 (buf1)
    FULLBAR(); RA_A2(1, 0, 1, aY); RA_B2(1, 1, bF1);
               STAGE_A2(0, 0); STAGE_A2(0, 1); STAGE_A2(0, 2); STAGE_A2(0, 3);
               ADVA(kt0 + 3); MFMA24(0, aX, bF0);
    FULLBAR(); RA_A2(1, 1, 0, aX); MFMA24(0, aY, bF1);
    FULLBAR(); RA_A2(1, 1, 1, aY); STAGE_B2(1, 0); STAGE_B2(1, 1);
               MFMA24(1, aX, bF0); VM4();
    FULLBAR(); RA_A2(0, 0, 0, aX); RA_B2(0, 0, bF0); STAGE_B2(1, 2);
               ADVB(kt0 + 4); MFMA24(1, aY, bF1);
  }

  asm volatile("s_waitcnt vmcnt(0)" ::: "memory");

#undef MFMA24
#undef RA_A2
#undef RA_B2
#undef STAGE_A2
#undef STAGE_B2
#undef ADVA
#undef ADVB
#undef FULLBAR
#undef VM6
#undef VM4

  // ---- epilogue: fp32 out [e*SEG + row][COUT] ----
#pragma unroll
  for (int m = 0; m < 8; ++m) {
    const int rowb = m0 + wm * 128 + m * 16 + ((lane >> 4) << 2);
#pragma unroll
    for (int n = 0; n < 6; ++n) {
      const int col = n0 + wn * 96 + n * 16 + l15;
      float* ob = Out + ((size_t)e * SEG + rowb) * COUT + col;
#pragma unroll
      for (int i = 0; i < 4; ++i) ob[(size_t)i * COUT] = acc[m][n][i];
    }
  }
}

extern "C" void kernel_launch(void* const* d_in, const int* in_sizes, int n_in,
                              void* d_out, int out_size, void* d_ws, size_t ws_size,
                              hipStream_t stream) {
  const float* inp = (const float*)d_in[0];
  // d_in[1] = fwd_expert_count (all SEG=2048, static per problem)
  const float* w1 = (const float*)d_in[2];
  const float* b1 = (const float*)d_in[3];
  const float* w2 = (const float*)d_in[4];
  const float* b2 = (const float*)d_in[5];
  float* out = (float*)d_out;
  char* ws = (char*)d_ws;

  const size_t szXp = (size_t)E_ * PSEG * D_ * 2;    // 25.2 MB
  const size_t szHp = (size_t)E_ * PSEG * H_ * 2;    // 100.8 MB
  const size_t szW1 = (size_t)E_ * H_ * 3 * D_ * 2;  // 113.2 MB
  const size_t szW2 = (size_t)E_ * D_ * 3 * H_ * 2;  // 113.2 MB

  unsigned short* Xp  = (unsigned short*)ws;
  unsigned short* Hp  = (unsigned short*)(ws + szXp);
  unsigned short* W1T = (unsigned short*)(ws + szXp + szHp);
  unsigned short* W2T = (unsigned short*)(ws + szXp + szHp + szW1);

  if (ws_size < szXp + szHp + szW1 + szW2) return;  // leaves zeros (diagnostic signature)

  zero_guards2_kernel<<<32, 256, 0, stream>>>(Xp, Hp);
  cvt_x_pad_kernel<<<T_ * D_ / 8 / 256, 256, 0, stream>>>(inp, Xp);
  cvt_w_kernel<D_><<<(E_ * H_) * (D_ / 8) / 256, 256, 0, stream>>>(w1, W1T);
  cvt_w_kernel<H_><<<(E_ * D_) * (H_ / 8) / 256, 256, 0, stream>>>(w2, W2T);

  constexpr int NWG1 = (H_ / 256) * (SEG / 256) * E_;  // 12*8*8 = 768 (3 rounds)
  constexpr int NWG2 = (D_ / 192) * (SEG / 256) * E_;  // 4*8*8  = 256 (1 round)
  conv_gemm4_kernel<D_, H_, true>
      <<<NWG1, 256, 0, stream>>>(Xp, W1T, b1, Hp);
  conv_gemm4_n192_kernel<H_, D_>
      <<<NWG2, 256, 0, stream>>>(Hp, W2T, b2, out);
}

// Round 12
// 508.008 us; speedup vs baseline: 1.4259x; 1.4259x over previous
//
#include <hip/hip_runtime.h>
#include <hip/hip_bf16.h>
#include <cstdint>

// Problem constants (static per reference: counts are all T/E = 2048)
#define E_   8
#define D_   768
#define H_   3072
#define T_   16384
#define SEG  2048
#define PSEG (SEG + 2)   // +1 zero guard row above and below each segment

typedef __attribute__((ext_vector_type(8))) __bf16 bf16x8;
typedef __attribute__((ext_vector_type(4))) float f32x4;
typedef __attribute__((ext_vector_type(4))) unsigned int u32x4;

__device__ inline unsigned short f2bf(float f) {
  union { float f; unsigned int u; } v; v.f = f;
  unsigned int u = v.u;
  u += 0x7fffu + ((u >> 16) & 1u);   // round-to-nearest-even
  return (unsigned short)(u >> 16);
}

// branch-free tanh-form GELU: x * sigmoid(1.5957691*x*(1+0.044715*x^2))
__device__ inline float gelu_fast(float x) {
  const float a = -2.302118131f;           // -2*0.7978845608*log2(e)
  const float b = -0.102944213f;           // a*0.044715
  float z = x * __builtin_fmaf(b, x * x, a);
  float e = __builtin_amdgcn_exp2f(z);
  return x * __builtin_amdgcn_rcpf(1.0f + e);
}

// packed f32x2 -> bf16x2 (RNE, same as f2bf); low 16 = s0, high 16 = s1
__device__ inline unsigned cvt_pk_bf16(float lo, float hi) {
  unsigned r;
  asm("v_cvt_pk_bf16_f32 %0, %1, %2" : "=v"(r) : "v"(lo), "v"(hi));
  return r;
}

// async global->LDS, 16B per lane; LDS dest is wave-uniform base + lane*16
__device__ inline void gload16(const unsigned short* g, unsigned short* l) {
  __builtin_amdgcn_global_load_lds(
      (const __attribute__((address_space(1))) unsigned int*)g,
      (__attribute__((address_space(3))) unsigned int*)l, 16, 0, 0);
}

// ============================================================================
// Fused prep kernel: guard-zeroing + cvt_x (padded bf16) + both weight
// transposes, range-dispatched on blockIdx. All parts write disjoint regions.
//   blocks [0,32):              guard rows of Xp/Hp
//   blocks [32, 32+6144):       cvt_x  (T*D/8 vec8 elements)
//   blocks [6176, 6176+9216):   cvt_w1 [E*H][D][3] -> [E*H][3][D]
//   blocks [15392, 15392+9216): cvt_w2 [E*D][H][3] -> [E*D][3][H]
// ============================================================================
template <int C>
__device__ inline void cvt_w_body(const float* __restrict__ in,
                                  unsigned short* __restrict__ out, int i) {
  constexpr int C8 = C / 8;
  const int row = i / C8;
  const int cq = i - row * C8;
  const float* src = in + ((size_t)row * C + cq * 8) * 3;
  unsigned short* dst = out + (size_t)row * 3 * C + cq * 8;
  f32x4 v[6];
#pragma unroll
  for (int j = 0; j < 6; ++j) v[j] = *(const f32x4*)(src + j * 4);
  const float* f = (const float*)v;
#pragma unroll
  for (int k = 0; k < 3; ++k) {
    u32x4 w;
#pragma unroll
    for (int j = 0; j < 4; ++j)
      w[j] = (unsigned)f2bf(f[(2 * j) * 3 + k]) |
             ((unsigned)f2bf(f[(2 * j + 1) * 3 + k]) << 16);
    *(u32x4*)(dst + k * C) = w;
  }
}

__global__ __launch_bounds__(256) void prep_kernel(
    const float* __restrict__ inp, const float* __restrict__ w1,
    const float* __restrict__ w2, unsigned short* __restrict__ Xp,
    unsigned short* __restrict__ Hp, unsigned short* __restrict__ W1T,
    unsigned short* __restrict__ W2T) {
  const int b = blockIdx.x;
  const int tid = threadIdx.x;
  if (b < 32) {
    // guard rows: b<16 -> Xp, else Hp
    unsigned short* buf = (b < 16) ? Xp : Hp;
    const int C = (b < 16) ? D_ : H_;
    const int bb = b & 15;
    const size_t row = (size_t)(bb >> 1) * PSEG + (bb & 1) * (PSEG - 1);
    for (int c = tid; c < C; c += 256) buf[row * C + c] = 0;
  } else if (b < 32 + 6144) {
    const int i = (b - 32) * 256 + tid;          // vec8 index, < T*D/8
    const int elem = i * 8;
    const int row = elem / D_;
    const int col = elem - row * D_;
    const int prow = (row >> 11) * PSEG + 1 + (row & (SEG - 1));
    const float* p = inp + (size_t)row * D_ + col;
    u32x4 v;
#pragma unroll
    for (int j = 0; j < 4; ++j)
      v[j] = (unsigned)f2bf(p[2 * j]) | ((unsigned)f2bf(p[2 * j + 1]) << 16);
    *(u32x4*)(Xp + (size_t)prow * D_ + col) = v;
  } else if (b < 32 + 6144 + 9216) {
    cvt_w_body<D_>(w1, W1T, (b - 6176) * 256 + tid);
  } else {
    cvt_w_body<H_>(w2, W2T, (b - 15392) * 256 + tid);
  }
}

// ============================================================================
// GEMM1: 256x256 8-phase conv-GEMM (round-10 verified kernel, byte-identical).
//   RA via 4 precomputed per-lane LDS pointers + compile-time offsets;
//   staging via uniform SGPR base + per-lane voffset; schedule/waits audited
//   (rounds 6/9/10): slots p0..p7, VM6@p0/p4, VM4@p2/p6.
// ============================================================================
template <int CIN, int COUT, bool DO_GELU>
__global__ __launch_bounds__(512, 2) void conv_gemm8_kernel(
    const unsigned short* __restrict__ A,
    const unsigned short* __restrict__ Bt,
    const float* __restrict__ bias,
    void* __restrict__ Out) {
  __shared__ __align__(16) unsigned short lds[65536];  // 128 KiB

  constexpr int CSTEPS = CIN / 64;
  constexpr int NT = 3 * CSTEPS;        // K-tiles
  constexpr int NTN = COUT / 256;       // n-tiles per expert

  const int tid  = threadIdx.x;
  const int wid  = tid >> 6, lane = tid & 63;
  const int wm   = wid >> 2, wn = wid & 3;

  const int bid = blockIdx.x;
  const int e   = bid & 7;              // expert == XCD
  const int rem = bid >> 3;             // 4-m-chunked
  const int mc  = rem / (4 * NTN);
  const int r2  = rem - mc * 4 * NTN;
  const int m0  = (mc * 4 + (r2 & 3)) * 256;
  const int n0  = (r2 >> 2) * 256;

  const int rowoff = tid >> 3;                         // 0..63: staging row
  const int psrc   = ((lane & 7) ^ (lane >> 3)) * 8;   // source-permuted piece (elems)
  const int ko     = (lane >> 4) * 16;                 // frag k-col byte offset
  const int ax     = (lane & 7) << 4;                  // read-side XOR
  const int l15    = lane & 15;

  // precomputed per-lane LDS read pointers (s*64 and ko are disjoint bits)
  const int koax0 = ko ^ ax;
  const int koax1 = (64 | ko) ^ ax;
  const char* pA0 = (const char*)lds + wm * 16384 + l15 * 128 + koax0;
  const char* pA1 = (const char*)lds + wm * 16384 + l15 * 128 + koax1;
  const char* pB0 = (const char*)lds + 65536 + (wn >> 1) * 16384 +
                    ((wn & 1) * 64 + l15) * 128 + koax0;
  const char* pB1 = (const char*)lds + 65536 + (wn >> 1) * 16384 +
                    ((wn & 1) * 64 + l15) * 128 + koax1;

  // staging: uniform base + per-lane 32-bit voffset (elements)
  const unsigned short* aU = A + ((size_t)e * PSEG + m0) * CIN;      // uniform
  const unsigned short* bU = Bt + (size_t)(e * COUT + n0) * 3 * CIN; // uniform
  const int avo = rowoff * CIN + psrc;                               // per-lane
  const int bvo = rowoff * 3 * CIN + psrc;                           // per-lane
  size_t aOff = 0, bOff = 0;                                         // uniform, +64/tile

  f32x4 acc[8][4];
#pragma unroll
  for (int n = 0; n < 4; ++n) {
    const float bv = bias[e * COUT + n0 + wn * 64 + n * 16 + l15];
#pragma unroll
    for (int m = 0; m < 8; ++m) acc[m][n] = (f32x4){bv, bv, bv, bv};
  }

#define STAGE_A(BUF_, part_) do {                                                    \
    _Pragma("unroll")                                                                \
    for (int ii_ = 0; ii_ < 2; ++ii_)                                                \
      gload16(aU + aOff + avo + (ii_ * 128 + (part_) * 64) * CIN,                    \
              (unsigned short*)((char*)lds + (BUF_) * 32768 + ii_ * 16384 +          \
                                (part_) * 8192 + wid * 1024 + lane * 16));           \
  } while (0)

#define STAGE_B(BUF_, h_) do {                                                       \
    _Pragma("unroll")                                                                \
    for (int ii_ = 0; ii_ < 2; ++ii_)                                                \
      gload16(bU + bOff + bvo + ((h_) * 128 + ii_ * 64) * 3 * CIN,                   \
              (unsigned short*)((char*)lds + 65536 + (BUF_) * 32768 + (h_) * 16384 + \
                                ii_ * 8192 + wid * 1024 + lane * 16));               \
  } while (0)

#define ADVA(nx_) do { if ((nx_) < NT) aOff += 64; } while (0)
#define ADVB(nx_) do { if ((nx_) < NT) bOff += 64; } while (0)

#define FULLBAR() do { asm volatile("" ::: "memory");                                \
                       __builtin_amdgcn_s_barrier();                                 \
                       asm volatile("" ::: "memory"); } while (0)
#define VM6() asm volatile("s_waitcnt vmcnt(6)" ::: "memory")
#define VM4() asm volatile("s_waitcnt vmcnt(4)" ::: "memory")
#define VM_NONE()

#define RA(buf_, mq_, s_, raA_, raB_, RB_) do {                                      \
    const char* pAx_ = (s_) ? pA1 : pA0;                                             \
    if (RB_) {                                                                       \
      const char* pBx_ = (s_) ? pB1 : pB0;                                           \
      _Pragma("unroll")                                                              \
      for (int n_ = 0; n_ < 4; ++n_)                                                 \
        raB_[n_] = *(const bf16x8*)(pBx_ + (buf_) * 32768 + n_ * 2048);              \
    }                                                                                \
    _Pragma("unroll")                                                                \
    for (int mi_ = 0; mi_ < 4; ++mi_)                                                \
      raA_[mi_] = *(const bf16x8*)(pAx_ + (buf_) * 32768 + ((mq_) * 4 + mi_) * 2048);\
  } while (0)

#define PHASE(raBuf_, raMq_, raS_, raA_, raB_, RB_, useA_, useB_, mq_, STAGE_STMT, VMW_) \
  do {                                                                               \
    FULLBAR();                                                                       \
    RA(raBuf_, raMq_, raS_, raA_, raB_, RB_);                                        \
    STAGE_STMT;                                                                      \
    __builtin_amdgcn_s_setprio(1);                                                   \
    _Pragma("unroll")                                                                \
    for (int mi_ = 0; mi_ < 4; ++mi_)                                                \
      _Pragma("unroll")                                                              \
      for (int n_ = 0; n_ < 4; ++n_)                                                 \
        acc[(mq_) * 4 + mi_][n_] = __builtin_amdgcn_mfma_f32_16x16x32_bf16(          \
            useA_[mi_], useB_[n_], acc[(mq_) * 4 + mi_][n_], 0, 0, 0);               \
    __builtin_amdgcn_s_setprio(0);                                                   \
    VMW_();                                                                          \
  } while (0)

  // ---- prologue (round-9/10 audited) ----
  STAGE_B(0, 0); STAGE_B(0, 1); ADVB(1);
  STAGE_A(0, 0); STAGE_A(0, 1); ADVA(1);
  STAGE_B(1, 0); STAGE_B(1, 1); ADVB(2);
  VM6();
  FULLBAR();

  bf16x8 aFA[4], aFB[4], bFA[4], bFB[4];
  RA(0, 0, 0, aFA, bFA, 1);

  int kt0 = 0;
#pragma unroll 1
  for (int it = 0; it < NT / 2; ++it, kt0 += 2) {
    PHASE(0, 0, 1, aFB, bFB, 1, aFA, bFA, 0, STAGE_A(1, 0), VM6);
    PHASE(0, 1, 0, aFA, bFA, 0, aFB, bFB, 0, { STAGE_A(1, 1); ADVA(kt0 + 2); }, VM_NONE);
    PHASE(0, 1, 1, aFB, bFB, 0, aFA, bFA, 1, STAGE_B(0, 0), VM4);
    PHASE(1, 0, 0, aFA, bFA, 1, aFB, bFB, 1, { STAGE_B(0, 1); ADVB(kt0 + 3); }, VM_NONE);
    PHASE(1, 0, 1, aFB, bFB, 1, aFA, bFA, 0, STAGE_A(0, 0), VM6);
    PHASE(1, 1, 0, aFA, bFA, 0, aFB, bFB, 0, { STAGE_A(0, 1); ADVA(kt0 + 3); }, VM_NONE);
    PHASE(1, 1, 1, aFB, bFB, 0, aFA, bFA, 1, STAGE_B(1, 0), VM4);
    PHASE(0, 0, 0, aFA, bFA, 1, aFB, bFB, 1, { STAGE_B(1, 1); ADVB(kt0 + 4); }, VM_NONE);
  }

  asm volatile("s_waitcnt vmcnt(0)" ::: "memory");

#undef PHASE
#undef RA
#undef STAGE_A
#undef STAGE_B
#undef ADVA
#undef ADVB

  // ---- epilogue: C/D layout col=lane&15, row=(lane>>4)*4+i; cvt_pk pairs ----
#pragma unroll
  for (int m = 0; m < 8; ++m) {
    const int rowb = m0 + wm * 128 + m * 16 + ((lane >> 4) << 2);
#pragma unroll
    for (int n = 0; n < 4; ++n) {
      const int col = n0 + wn * 64 + n * 16 + l15;
      if (DO_GELU) {
        unsigned short* ob = (unsigned short*)Out +
                             ((size_t)e * PSEG + 1 + rowb) * COUT + col;
#pragma unroll
        for (int i = 0; i < 4; i += 2) {
          const unsigned pk = cvt_pk_bf16(gelu_fast(acc[m][n][i]),
                                          gelu_fast(acc[m][n][i + 1]));
          ob[(size_t)i * COUT] = (unsigned short)pk;
          ob[(size_t)(i + 1) * COUT] = (unsigned short)(pk >> 16);
        }
      } else {
        float* ob = (float*)Out + ((size_t)e * SEG + rowb) * COUT + col;
#pragma unroll
        for (int i = 0; i < 4; ++i) ob[(size_t)i * COUT] = acc[m][n][i];
      }
    }
  }
#undef FULLBAR
#undef VM6
#undef VM4
#undef VM_NONE
}

// ============================================================================
// GEMM2: 256x192-tile conv-GEMM -> 256 blocks (round-10 verified kernel).
// ============================================================================
template <int CIN, int COUT>
__global__ __launch_bounds__(512, 2) void conv_gemm_n192_kernel(
    const unsigned short* __restrict__ A,
    const unsigned short* __restrict__ Bt,
    const float* __restrict__ bias,
    float* __restrict__ Out) {
  __shared__ __align__(16) unsigned short lds[57344];  // 112 KiB

  constexpr int CSTEPS = CIN / 64;      // 48
  constexpr int NT = 3 * CSTEPS;        // 144

  const int tid  = threadIdx.x;
  const int wid  = tid >> 6, lane = tid & 63;
  const int wm   = wid >> 2, wn = wid & 3;

  const int bid = blockIdx.x;
  const int e   = bid & 7;              // expert == XCD (32 blocks/XCD = 32 CUs)
  const int rem = bid >> 3;             // 0..31: m-inner (8) x n (4)
  const int m0  = (rem & 7) * 256;
  const int n0  = (rem >> 3) * 192;

  const int rowoff = tid >> 3;
  const int psrc   = ((lane & 7) ^ (lane >> 3)) * 8;
  const int ko     = (lane >> 4) * 16;
  const int ax     = (lane & 7) << 4;
  const int l15    = lane & 15;

  const int koax0 = ko ^ ax;
  const int koax1 = (64 | ko) ^ ax;
  const char* pA0 = (const char*)lds + wm * 16384 + l15 * 128 + koax0;
  const char* pA1 = (const char*)lds + wm * 16384 + l15 * 128 + koax1;
  const char* pB0 = (const char*)lds + 65536 + wn * 6144 + l15 * 128 + koax0;
  const char* pB1 = (const char*)lds + 65536 + wn * 6144 + l15 * 128 + koax1;

  const unsigned short* aU = A + ((size_t)e * PSEG + m0) * CIN;      // uniform
  const unsigned short* bU = Bt + (size_t)(e * COUT + n0) * 3 * CIN; // uniform
  const int avo = rowoff * CIN + psrc;
  const int bvo = rowoff * 3 * CIN + psrc;
  size_t aOff = 0, bOff = 0;

  f32x4 acc[8][3];
#pragma unroll
  for (int n = 0; n < 3; ++n) {
    const float bv = bias[e * COUT + n0 + wn * 48 + n * 16 + l15];
#pragma unroll
    for (int m = 0; m < 8; ++m) acc[m][n] = (f32x4){bv, bv, bv, bv};
  }

#define ADVA(nx_) do { if ((nx_) < NT) aOff += 64; } while (0)
#define ADVB(nx_) do { if ((nx_) < NT) bOff += 64; } while (0)

#define STAGE_A2(BUF_, slot_)                                                        \
  gload16(aU + aOff + avo + ((slot_) * 64) * CIN,                                    \
          (unsigned short*)((char*)lds + (BUF_) * 32768 + (slot_) * 8192 +           \
                            wid * 1024 + lane * 16))
#define STAGE_B2(BUF_, slot_)                                                        \
  gload16(bU + bOff + bvo + ((slot_) * 64) * 3 * CIN,                                \
          (unsigned short*)((char*)lds + 65536 + (BUF_) * 24576 + (slot_) * 8192 +   \
                            wid * 1024 + lane * 16))

#define FULLBAR() do { asm volatile("" ::: "memory");                                \
                       __builtin_amdgcn_s_barrier();                                 \
                       asm volatile("" ::: "memory"); } while (0)
#define VM3() asm volatile("s_waitcnt vmcnt(3)" ::: "memory")
#define VM2() asm volatile("s_waitcnt vmcnt(2)" ::: "memory")

#define RA_A2(buf_, mq_, s_, dst_) do {                                              \
    const char* pAx_ = (s_) ? pA1 : pA0;                                             \
    _Pragma("unroll")                                                                \
    for (int mi_ = 0; mi_ < 4; ++mi_)                                                \
      dst_[mi_] = *(const bf16x8*)(pAx_ + (buf_) * 32768 + ((mq_) * 4 + mi_) * 2048);\
  } while (0)

#define RA_B2(buf_, s_, dst_) do {                                                   \
    const char* pBx_ = (s_) ? pB1 : pB0;                                             \
    _Pragma("unroll")                                                                \
    for (int n_ = 0; n_ < 3; ++n_)                                                   \
      dst_[n_] = *(const bf16x8*)(pBx_ + (buf_) * 24576 + n_ * 2048);                \
  } while (0)

#define MFMA12(mq_, aU_, bU_) do {                                                   \
    __builtin_amdgcn_s_setprio(1);                                                   \
    _Pragma("unroll")                                                                \
    for (int mi_ = 0; mi_ < 4; ++mi_)                                                \
      _Pragma("unroll")                                                              \
      for (int n_ = 0; n_ < 3; ++n_)                                                 \
        acc[(mq_) * 4 + mi_][n_] = __builtin_amdgcn_mfma_f32_16x16x32_bf16(          \
            aU_[mi_], bU_[n_], acc[(mq_) * 4 + mi_][n_], 0, 0, 0);                   \
    __builtin_amdgcn_s_setprio(0);                                                   \
  } while (0)

  // ---- prologue: A(0)x4, B(0)x3, B(1)x3; vmcnt(3) keeps B(1); barrier; prime ----
  STAGE_A2(0, 0); STAGE_A2(0, 1); STAGE_A2(0, 2); STAGE_A2(0, 3); ADVA(1);
  STAGE_B2(0, 0); STAGE_B2(0, 1); STAGE_B2(0, 2); ADVB(1);
  STAGE_B2(1, 0); STAGE_B2(1, 1); STAGE_B2(1, 2); ADVB(2);
  VM3();
  FULLBAR();

  bf16x8 aX[4], aY[4], bF0[3], bF1[3];
  RA_A2(0, 0, 0, aX);
  RA_B2(0, 0, bF0);

  int kt0 = 0;
#pragma unroll 1
  for (int it = 0; it < NT / 2; ++it, kt0 += 2) {
    // tile t (buf0)
    FULLBAR(); RA_A2(0, 0, 1, aY); RA_B2(0, 1, bF1);
               STAGE_A2(1, 0); STAGE_A2(1, 1); STAGE_A2(1, 2); STAGE_A2(1, 3);
               ADVA(kt0 + 2); MFMA12(0, aX, bF0);
    FULLBAR(); RA_A2(0, 1, 0, aX); MFMA12(0, aY, bF1);
    FULLBAR(); RA_A2(0, 1, 1, aY); STAGE_B2(0, 0); STAGE_B2(0, 1);
               MFMA12(1, aX, bF0); VM2();
    FULLBAR(); RA_A2(1, 0, 0, aX); RA_B2(1, 0, bF0); STAGE_B2(0, 2);
               ADVB(kt0 + 3); MFMA12(1, aY, bF1);
    // tile t+1 (buf1)
    FULLBAR(); RA_A2(1, 0, 1, aY); RA_B2(1, 1, bF1);
               STAGE_A2(0, 0); STAGE_A2(0, 1); STAGE_A2(0, 2); STAGE_A2(0, 3);
               ADVA(kt0 + 3); MFMA12(0, aX, bF0);
    FULLBAR(); RA_A2(1, 1, 0, aX); MFMA12(0, aY, bF1);
    FULLBAR(); RA_A2(1, 1, 1, aY); STAGE_B2(1, 0); STAGE_B2(1, 1);
               MFMA12(1, aX, bF0); VM2();
    FULLBAR(); RA_A2(0, 0, 0, aX); RA_B2(0, 0, bF0); STAGE_B2(1, 2);
               ADVB(kt0 + 4); MFMA12(1, aY, bF1);
  }

  asm volatile("s_waitcnt vmcnt(0)" ::: "memory");

#undef MFMA12
#undef RA_A2
#undef RA_B2
#undef STAGE_A2
#undef STAGE_B2
#undef ADVA
#undef ADVB
#undef FULLBAR
#undef VM3
#undef VM2

  // ---- epilogue: fp32 out [e*SEG + row][COUT] ----
#pragma unroll
  for (int m = 0; m < 8; ++m) {
    const int rowb = m0 + wm * 128 + m * 16 + ((lane >> 4) << 2);
#pragma unroll
    for (int n = 0; n < 3; ++n) {
      const int col = n0 + wn * 48 + n * 16 + l15;
      float* ob = Out + ((size_t)e * SEG + rowb) * COUT + col;
#pragma unroll
      for (int i = 0; i < 4; ++i) ob[(size_t)i * COUT] = acc[m][n][i];
    }
  }
}

extern "C" void kernel_launch(void* const* d_in, const int* in_sizes, int n_in,
                              void* d_out, int out_size, void* d_ws, size_t ws_size,
                              hipStream_t stream) {
  const float* inp = (const float*)d_in[0];
  // d_in[1] = fwd_expert_count (all SEG=2048, static per problem)
  const float* w1 = (const float*)d_in[2];
  const float* b1 = (const float*)d_in[3];
  const float* w2 = (const float*)d_in[4];
  const float* b2 = (const float*)d_in[5];
  float* out = (float*)d_out;
  char* ws = (char*)d_ws;

  const size_t szXp = (size_t)E_ * PSEG * D_ * 2;    // 25.2 MB
  const size_t szHp = (size_t)E_ * PSEG * H_ * 2;    // 100.8 MB
  const size_t szW1 = (size_t)E_ * H_ * 3 * D_ * 2;  // 113.2 MB
  const size_t szW2 = (size_t)E_ * D_ * 3 * H_ * 2;  // 113.2 MB

  unsigned short* Xp  = (unsigned short*)ws;
  unsigned short* Hp  = (unsigned short*)(ws + szXp);
  unsigned short* W1T = (unsigned short*)(ws + szXp + szHp);
  unsigned short* W2T = (unsigned short*)(ws + szXp + szHp + szW1);

  if (ws_size < szXp + szHp + szW1 + szW2) return;  // leaves zeros (diagnostic signature)

  // one fused prep launch: guards + cvt_x + cvt_w1 + cvt_w2
  constexpr int PREP_BLOCKS = 32 + (T_ * D_ / 8 / 256)               // 32 + 6144
                            + (E_ * H_) * (D_ / 8) / 256             // + 9216
                            + (E_ * D_) * (H_ / 8) / 256;            // + 9216
  prep_kernel<<<PREP_BLOCKS, 256, 0, stream>>>(inp, w1, w2, Xp, Hp, W1T, W2T);

  constexpr int NWG1 = (H_ / 256) * (SEG / 256) * E_;  // 12*8*8 = 768 (3 rounds)
  constexpr int NWG2 = (D_ / 192) * (SEG / 256) * E_;  // 4*8*8  = 256 (1 round)
  conv_gemm8_kernel<D_, H_, true>
      <<<NWG1, 512, 0, stream>>>(Xp, W1T, b1, Hp);
  conv_gemm_n192_kernel<H_, D_>
      <<<NWG2, 512, 0, stream>>>(Hp, W2T, b2, out);
}